// Round 7
// baseline (293.128 us; speedup 1.0000x reference)
//
#include <hip/hip_runtime.h>

// AWQ int4 GEMM: out[M,N] = x[M,K] @ dequant(qweight,qzeros,scales)
// M=2048 K=4096 N=11008 G=128.
// TWO-PASS: (1) x fp32->f16 images; (2) W dequant once -> f16 images;
// (3) counted-vmcnt raw-barrier double-buffered gload_lds MFMA GEMM,
//     BM=128 BN=256 BK=64, 8 waves, 96KB LDS, grid 16x43=688.

#define MDIM 2048
#define KDIM 4096
#define NDIM 11008
#define NPC  1376          // N/8 packed columns
#define NT   64            // K / 64
#define BM   128
#define BN   256
#define BK   64

typedef _Float16 half8   __attribute__((ext_vector_type(8)));
typedef _Float16 half2v  __attribute__((ext_vector_type(2)));
typedef __fp16   fp16x2n __attribute__((ext_vector_type(2)));
typedef float    f32x4   __attribute__((ext_vector_type(4)));

__device__ __forceinline__ half2v u2h(unsigned u) { union { unsigned u; half2v h; } v; v.u = u; return v.h; }
__device__ __forceinline__ unsigned h2u(half2v h) { union { unsigned u; half2v h; } v; v.h = h; return v.u; }
__device__ __forceinline__ unsigned pkrtz(float a, float b) {
    union { fp16x2n h; unsigned u; } v;
    v.h = __builtin_amdgcn_cvt_pkrtz(a, b);
    return v.u;
}

// ============ pass 1: x fp32 -> f16 images, 128-row tiles ============
// image per (mb 0..15, kt 0..63): [r 0..127][slot' = s^(r&7)][8 half] = 16KB
__global__ __launch_bounds__(256) void xconv128(const float* __restrict__ x,
                                                _Float16* __restrict__ xi) {
    const int id = blockIdx.x * 256 + threadIdx.x;   // 2^20
    const int s  = id & 7;
    const int r  = (id >> 3) & 127;
    const int kt = (id >> 10) & 63;
    const int mb = id >> 16;
    const float* src = x + (size_t)(mb * 128 + r) * KDIM + kt * 64 + s * 8;
    const float4 f0 = *(const float4*)src;
    const float4 f1 = *(const float4*)(src + 4);
    uint4 w;
    w.x = pkrtz(f0.x, f0.y); w.y = pkrtz(f0.z, f0.w);
    w.z = pkrtz(f1.x, f1.y); w.w = pkrtz(f1.z, f1.w);
    const size_t off = ((size_t)(mb * 64 + kt) * 128 + r) * 64 + (size_t)((s ^ (r & 7)) * 8);
    *(uint4*)(xi + off) = w;
}

// ============ pass 2: W dequant ONCE -> f16 images ============
// image per (nb128 0..85, kt 0..63): [n 0..127][slot' = s ^ ((n&7)^((n>>3)&7))][8] = 16KB
__global__ __launch_bounds__(256)
void wdeq(const int* __restrict__ qw, const unsigned* __restrict__ qz,
          const float* __restrict__ sc, _Float16* __restrict__ wi)
{
    __shared__ _Float16 img[2 * 8192];   // 32KB = 2 images

    const int t   = threadIdx.x;
    const int pcL = t & 15;
    const int kbL = t >> 4;
    const int nb  = blockIdx.x;          // 0..85
    const int by  = blockIdx.y;          // 0..31 (= group g)
    const int pcg = nb * 16 + pcL;
    const int kb  = by * 16 + kbL;       // k-octet, k0 = kb*8

    const int* qp = qw + (size_t)(kb * 8) * NPC + pcg;
    unsigned w[8];
    #pragma unroll
    for (int r = 0; r < 8; ++r) w[r] = (unsigned)qp[(size_t)r * NPC];
    const unsigned rz = qz[(size_t)by * NPC + pcg];
    const float* sp = sc + (size_t)by * NDIM + pcg * 8;
    const float4 rs0 = *(const float4*)sp;
    const float4 rs1 = *(const float4*)(sp + 4);

    const int kt2 = kbL >> 3;            // which of the 2 LDS images
    const int s   = kbL & 7;             // k-slot in image
    const unsigned M_ = 0x000F000Fu, G_ = 0x64006400u;

    #pragma unroll
    for (int p = 0; p < 4; ++p) {        // n-pair (2p, 2p+1)
        const unsigned zp  = ((rz >> (4 * p)) & M_) | G_;
        const unsigned spk = (p == 0) ? pkrtz(rs0.x, rs0.y)
                           : (p == 1) ? pkrtz(rs0.z, rs0.w)
                           : (p == 2) ? pkrtz(rs1.x, rs1.y)
                                      : pkrtz(rs1.z, rs1.w);
        unsigned d[8];
        #pragma unroll
        for (int r = 0; r < 8; ++r)
            d[r] = h2u((u2h(((w[r] >> (4 * p)) & M_) | G_) - u2h(zp)) * u2h(spk));
        uint4 ev, od;
        ev.x = __builtin_amdgcn_perm(d[1], d[0], 0x05040100u);
        ev.y = __builtin_amdgcn_perm(d[3], d[2], 0x05040100u);
        ev.z = __builtin_amdgcn_perm(d[5], d[4], 0x05040100u);
        ev.w = __builtin_amdgcn_perm(d[7], d[6], 0x05040100u);
        od.x = __builtin_amdgcn_perm(d[1], d[0], 0x07060302u);
        od.y = __builtin_amdgcn_perm(d[3], d[2], 0x07060302u);
        od.z = __builtin_amdgcn_perm(d[5], d[4], 0x07060302u);
        od.w = __builtin_amdgcn_perm(d[7], d[6], 0x07060302u);
        const int ne = pcL * 8 + 2 * p, no = ne + 1;
        const int swe = (ne & 7) ^ ((ne >> 3) & 7);
        const int swo = (no & 7) ^ ((no >> 3) & 7);
        *(uint4*)((char*)img + kt2 * 16384 + ne * 128 + ((s ^ swe) * 16)) = ev;
        *(uint4*)((char*)img + kt2 * 16384 + no * 128 + ((s ^ swo) * 16)) = od;
    }
    __syncthreads();

    _Float16* dst = wi + (size_t)(nb * 64 + by * 2) * 8192;
    #pragma unroll
    for (int i = 0; i < 8; ++i) {
        const int idx = i * 256 + t;
        *(uint4*)((char*)dst + idx * 16) = *(const uint4*)((const char*)img + idx * 16);
    }
}

// ============ pass 3: counted-vmcnt double-buffered GEMM ============
__global__ __launch_bounds__(512, 2)
void awq_gemm3(const _Float16* __restrict__ xi,
               const _Float16* __restrict__ wi,
               float* __restrict__ out)
{
    __shared__ _Float16 As[2][BM * BK];   // 16KB each
    __shared__ _Float16 Bs[2][BN * BK];   // 32KB each

    const int t    = threadIdx.x;
    const int lane = t & 63;
    const int wave = t >> 6;           // 0..7
    const int WR   = wave & 1;         // 2 M-bands of 64
    const int WC   = wave >> 1;        // 4 N-bands of 64

    const int mb = blockIdx.x;         // 0..15
    const int nb = blockIdx.y;         // 0..42
    const int m0 = mb * BM;
    const int n0 = nb * BN;

    // per-thread global/LDS staging bases
    const _Float16* aBase  = xi + (size_t)mb * NT * 8192 + t * 8;
    const _Float16* bBase0 = wi + (size_t)(2 * nb)     * NT * 8192 + t * 8;
    const _Float16* bBase1 = wi + (size_t)(2 * nb + 1) * NT * 8192 + t * 8;

    f32x4 acc[4][4];
    #pragma unroll
    for (int i = 0; i < 4; ++i)
        #pragma unroll
        for (int j = 0; j < 4; ++j)
            acc[i][j] = (f32x4){0.f, 0.f, 0.f, 0.f};

#define ISSUE(TT, Ab, Bb) do {                                                \
    const _Float16* a_ = aBase  + (size_t)(TT) * 8192;                        \
    const _Float16* b0 = bBase0 + (size_t)(TT) * 8192;                        \
    const _Float16* b1 = bBase1 + (size_t)(TT) * 8192;                        \
    char* ad = (char*)(Ab) + t * 16;                                          \
    char* bd = (char*)(Bb) + t * 16;                                          \
    __builtin_amdgcn_global_load_lds((const __attribute__((address_space(1))) void*)(a_),        (__attribute__((address_space(3))) void*)(ad),         16, 0, 0); \
    __builtin_amdgcn_global_load_lds((const __attribute__((address_space(1))) void*)(a_ + 4096), (__attribute__((address_space(3))) void*)(ad + 8192),  16, 0, 0); \
    __builtin_amdgcn_global_load_lds((const __attribute__((address_space(1))) void*)(b0),        (__attribute__((address_space(3))) void*)(bd),         16, 0, 0); \
    __builtin_amdgcn_global_load_lds((const __attribute__((address_space(1))) void*)(b0 + 4096), (__attribute__((address_space(3))) void*)(bd + 8192),  16, 0, 0); \
    __builtin_amdgcn_global_load_lds((const __attribute__((address_space(1))) void*)(b1),        (__attribute__((address_space(3))) void*)(bd + 16384), 16, 0, 0); \
    __builtin_amdgcn_global_load_lds((const __attribute__((address_space(1))) void*)(b1 + 4096), (__attribute__((address_space(3))) void*)(bd + 24576), 16, 0, 0); \
} while (0)

#define COMPUTE(Ab, Bb) do {                                                  \
    _Pragma("unroll")                                                         \
    for (int ks = 0; ks < 2; ++ks) {                                          \
        const int slot = ks * 4 + (lane >> 4);                                \
        half8 bfr[4];                                                         \
        _Pragma("unroll")                                                     \
        for (int j = 0; j < 4; ++j) {                                         \
            const int n  = WC * 64 + j * 16 + (lane & 15);                    \
            const int sw = (n & 7) ^ ((n >> 3) & 7);                          \
            bfr[j] = *(const half8*)((const char*)(Bb) + n * 128 + ((slot ^ sw) * 16)); \
        }                                                                     \
        __builtin_amdgcn_s_setprio(1);                                        \
        _Pragma("unroll")                                                     \
        for (int i = 0; i < 4; ++i) {                                         \
            const int row = WR * 64 + i * 16 + (lane & 15);                   \
            const half8 af = *(const half8*)((const char*)(Ab) + row * 128 + ((slot ^ (row & 7)) * 16)); \
            _Pragma("unroll")                                                 \
            for (int j = 0; j < 4; ++j)                                       \
                acc[i][j] = __builtin_amdgcn_mfma_f32_16x16x32_f16(           \
                    af, bfr[j], acc[i][j], 0, 0, 0);                          \
        }                                                                     \
        __builtin_amdgcn_s_setprio(0);                                        \
    }                                                                         \
} while (0)

    // prologue: 2 tiles in flight (12 loads/thread)
    ISSUE(0, As[0], Bs[0]);
    ISSUE(1, As[1], Bs[1]);

    for (int tt = 0; tt < NT; ++tt) {
        if (tt < NT - 1) {
            asm volatile("s_waitcnt vmcnt(6)" ::: "memory");   // own tile-tt loads done
        } else {
            asm volatile("s_waitcnt vmcnt(0)" ::: "memory");   // tail drain
        }
        __builtin_amdgcn_sched_barrier(0);
        __builtin_amdgcn_s_barrier();                          // ALL waves: tile tt resident
        __builtin_amdgcn_sched_barrier(0);

        COMPUTE(As[tt & 1], Bs[tt & 1]);

        __builtin_amdgcn_sched_barrier(0);
        __builtin_amdgcn_s_barrier();                          // all done READING buf
        __builtin_amdgcn_sched_barrier(0);

        if (tt + 2 < NT) {
            ISSUE(tt + 2, As[tt & 1], Bs[tt & 1]);             // overwrite published buf
        }
    }

    // epilogue: C/D layout col=lane&15, row=(lane>>4)*4+e
    const int crow = (lane >> 4) * 4;
    const int ccol = lane & 15;
    #pragma unroll
    for (int i = 0; i < 4; ++i) {
        #pragma unroll
        for (int j = 0; j < 4; ++j) {
            const size_t base =
                (size_t)(m0 + WR * 64 + i * 16 + crow) * NDIM +
                (n0 + WC * 64 + j * 16 + ccol);
            #pragma unroll
            for (int e = 0; e < 4; ++e)
                out[base + (size_t)e * NDIM] = acc[i][j][e];
        }
    }
#undef ISSUE
#undef COMPUTE
}

extern "C" void kernel_launch(void* const* d_in, const int* in_sizes, int n_in,
                              void* d_out, int out_size, void* d_ws, size_t ws_size,
                              hipStream_t stream) {
    const float*    x  = (const float*)d_in[0];
    const int*      qw = (const int*)d_in[1];
    const unsigned* qz = (const unsigned*)d_in[2];
    const float*    sc = (const float*)d_in[3];
    float* out = (float*)d_out;

    const size_t XI = (size_t)MDIM * KDIM * 2;          // 16.8 MB f16 x images
    const size_t WI = (size_t)86 * 64 * 16384;          // 90.2 MB f16 W images
    if (ws_size < XI + WI) return;                      // ws proven sufficient (R5/R6)

    _Float16* xi = (_Float16*)d_ws;
    _Float16* wi = (_Float16*)((char*)d_ws + XI);

    xconv128<<<4096, 256, 0, stream>>>(x, xi);
    wdeq<<<dim3(86, 32), 256, 0, stream>>>(qw, qz, sc, wi);
    awq_gemm3<<<dim3(16, 43), 512, 0, stream>>>(xi, wi, out);
}